// Round 6
// baseline (253.601 us; speedup 1.0000x reference)
//
#include <hip/hip_runtime.h>

#define T_DIM 4000
#define B_DIM 64
#define C_DIM 64
#define U_DIM 200
#define LOG2E 1.4426950408889634f
#define LN2 0.6931471805599453f

#define PAIRS 2000                 // pair tp = (t=2tp, t=2tp+1); no pad row
#define PB_BYTES (PAIRS * 800)     // 1.6 MB per batch (50 lanes x 16 B per pair)
#define NSLOT 20                   // uint4 slots per direction: 40 steps in flight

__device__ __forceinline__ float hw_exp2(float x) { return __builtin_amdgcn_exp2f(x); }
__device__ __forceinline__ float hw_log2(float x) { return __builtin_amdgcn_logf(x); }

// DPP: zero-fill (bound_ctrl) lane permute, pure VALU. 0x138=wave_shr:1 (lane l <- l-1),
// 0x130=wave_shl:1 (lane l <- l+1).
template <int CTRL>
__device__ __forceinline__ int dpp_i(int x) {
    return __builtin_amdgcn_update_dpp(0, x, CTRL, 0xF, 0xF, true);
}
template <int CTRL>
__device__ __forceinline__ float dpp_f(float x) {
    return __uint_as_float((unsigned)dpp_i<CTRL>((int)__float_as_uint(x)));
}

__device__ __forceinline__ unsigned rne_bf16(float v) {   // RNE bf16 in hi16
    unsigned b = __float_as_uint(v);
    return b + 0x7FFFu + ((b >> 16) & 1u);
}

// ---------------- prep: coalesced stage -> bf16 LDS tile -> Eg emit + row-lse ----------------
// (R5-proven, absmax 0.0) Block = (bg 0..7, tc 0..249).
__global__ __launch_bounds__(256, 8) void prep_kernel(const float* __restrict__ in,
                                                      const int* __restrict__ tgt,
                                                      unsigned* __restrict__ eg,
                                                      float* __restrict__ out) {
    __shared__ unsigned short exh[16 * 8 * 68];   // bf16 hi16, 68-stride pad
    __shared__ unsigned tgc[400];                 // uchar4-packed targets for 8 batches
    __shared__ float red[4];
    const int tid = threadIdx.x;
    const int bg = blockIdx.x & 7;
    const int tc = blockIdx.x >> 3;
    const int t0 = tc * 16, b0 = bg * 8;

    for (int o = tid; o < 400; o += 256) {
        int4 tv = ((const int4*)tgt)[bg * 400 + o];
        tgc[o] = (unsigned)(tv.x & 63) | ((unsigned)(tv.y & 63) << 8)
               | ((unsigned)(tv.z & 63) << 16) | ((unsigned)(tv.w & 63) << 24);
    }
    #pragma unroll
    for (int k = 0; k < 8; ++k) {
        int flat = k * 256 + tid;              // 0..2047
        int t_l = flat >> 7, i = flat & 127, b_l = i >> 4, q = i & 15;
        float4 v = *(const float4*)(in + (size_t)(t0 + t_l) * 4096 + (b0 + b_l) * 64 + q * 4);
        unsigned ex0 = rne_bf16(hw_exp2(v.x * LOG2E));
        unsigned ex1 = rne_bf16(hw_exp2(v.y * LOG2E));
        unsigned ex2 = rne_bf16(hw_exp2(v.z * LOG2E));
        unsigned ex3 = rne_bf16(hw_exp2(v.w * LOG2E));
        uint2 pk;
        pk.x = (ex0 >> 16) | (ex1 & 0xFFFF0000u);
        pk.y = (ex2 >> 16) | (ex3 & 0xFFFF0000u);
        *(uint2*)&exh[(t_l * 8 + b_l) * 68 + q * 4] = pk;
    }
    __syncthreads();

    {
        float v = 0.0f;
        if (tid < 128) {
            const unsigned* p = (const unsigned*)&exh[tid * 68];
            float s = 0.0f;
            #pragma unroll
            for (int j = 0; j < 32; ++j) {
                unsigned u = p[j];
                s += __uint_as_float(u << 16) + __uint_as_float(u & 0xFFFF0000u);
            }
            v = hw_log2(s);
        }
        #pragma unroll
        for (int o = 32; o > 0; o >>= 1) v += __shfl_xor(v, o);
        if ((tid & 63) == 0) red[tid >> 6] = v;
    }

    {
        const int wv4 = tid >> 6;      // wave 0..3
        const int ln = tid & 63;
        for (int r = wv4; r < 64; r += 4) {
            int b_l = r & 7, tp_l = r >> 3;
            if (ln < 50) {
                unsigned tw = tgc[b_l * 50 + ln];
                int c0 = tw & 255, c1 = (tw >> 8) & 255, c2 = (tw >> 16) & 255, c3 = tw >> 24;
                const unsigned short* plo = &exh[(tp_l * 16 + b_l) * 68];   // t = 2*tp_l
                const unsigned short* phi = plo + 8 * 68;                   // t = 2*tp_l + 1
                uint4 w;
                w.x = (unsigned)plo[c0] | ((unsigned)plo[c1] << 16);
                w.y = (unsigned)plo[c2] | ((unsigned)plo[c3] << 16);
                w.z = (unsigned)phi[c0] | ((unsigned)phi[c1] << 16);
                w.w = (unsigned)phi[c2] | ((unsigned)phi[c3] << 16);
                *(uint4*)((char*)eg + (size_t)(b0 + b_l) * PB_BYTES
                          + (size_t)(tc * 8 + tp_l) * 800 + ln * 16) = w;
            }
        }
    }
    __syncthreads();
    if (tid == 0)
        atomicAdd(out, (red[0] + red[1] + red[2] + red[3]) * (LN2 / 64.0f));
}

// ---- forward scan core (R0-proven, absmax 0.0) ----
struct ScanState { float A0, A1, A2, A3; int S, D; };

__device__ __forceinline__ void renorm(ScanState& st, int lane) {
    float m = fmaxf(fmaxf(st.A0, st.A1), fmaxf(st.A2, st.A3));
    int e = (int)((__float_as_uint(m) >> 23) & 0xFFu);
    int cand = st.S + e - 127;
    int snb = dpp_i<0x138>(st.S);
    if (lane == 0) snb = -(1 << 28);
    int snew = max(cand, snb);
    int k = st.S - snew;
    st.A0 = ldexpf(st.A0, k);
    st.A1 = ldexpf(st.A1, k);
    st.A2 = ldexpf(st.A2, k);
    st.A3 = ldexpf(st.A3, k);
    st.S = snew;
    st.D = min(dpp_i<0x138>(snew) - snew, 60);
}

__device__ __forceinline__ void step(ScanState& st, float e0, float e1, float e2, float e3) {
    float sh = ldexpf(dpp_f<0x138>(st.A3), st.D);
    sh = fminf(sh, 1.125899906842624e15f);         // 2^50; fminf absorbs inf
    float t0 = st.A0 + sh;
    float t1 = st.A1 + st.A0;
    float t2 = st.A2 + st.A1;
    float t3 = st.A3 + st.A2;
    st.A0 = e0 * t0; st.A1 = e1 * t1; st.A2 = e2 * t2; st.A3 = e3 * t3;
}

// ---- backward core: beta^T <- beta^T M_t; cross-lane term from lane l+1 via 0x130 ----
__device__ __forceinline__ void brenorm(ScanState& st) {
    float m = fmaxf(fmaxf(st.A0, st.A1), fmaxf(st.A2, st.A3));
    int e = (int)((__float_as_uint(m) >> 23) & 0xFFu);
    int cand = st.S + e - 127;
    int snb = dpp_i<0x130>(st.S);                  // lane63 gets 0 (junk side, harmless)
    int snew = max(cand, snb);
    int k = st.S - snew;
    st.A0 = ldexpf(st.A0, k);
    st.A1 = ldexpf(st.A1, k);
    st.A2 = ldexpf(st.A2, k);
    st.A3 = ldexpf(st.A3, k);
    st.S = snew;
    st.D = min(dpp_i<0x130>(snew) - snew, 60);
}

__device__ __forceinline__ void bstep(ScanState& st, float e0, float e1, float e2, float e3) {
    float e4s = fminf(ldexpf(dpp_f<0x130>(e0), st.D), 1.125899906842624e15f);
    float b0n = dpp_f<0x130>(st.A0);
    float g0 = e0 * st.A0, g1 = e1 * st.A1, g2 = e2 * st.A2, g3 = e3 * st.A3;
    st.A0 = g0 + g1; st.A1 = g1 + g2; st.A2 = g2 + g3; st.A3 = g3 + e4s * b0n;
}

__device__ __forceinline__ ScanState scan_init(const float* in, const int* tgt, int lane, int b) {
    float v0 = in[b * 64 + (tgt[b * U_DIM] & 63)];
    ScanState st;
    st.A0 = (lane == 0) ? hw_exp2(v0 * LOG2E) : 0.0f;
    st.A1 = 0.0f; st.A2 = 0.0f; st.A3 = 0.0f;
    st.S = 0; st.D = 0;
    return st;
}

#define LO(x) __uint_as_float((x) << 16)
#define HI(x) __uint_as_float((x) & 0xFFFF0000u)

// Dual-stream meet-in-the-middle: ONE 64-thread wave per batch carries BOTH the forward
// scan (t=1..2000) and backward scan (t=3999..2001) in disjoint registers, interleaved
// per j so each stream's dependency stalls are filled by the other stream's independent
// ops. Each stream's op sequence is textually identical to the proven 2-wave version
// (bit-identical result). Junction dot-product is in-register; no LDS, no barrier.
__global__ __launch_bounds__(64, 1) void scan2_kernel(const float* __restrict__ in,
                                                      const int* __restrict__ tgt,
                                                      const unsigned* __restrict__ eg,
                                                      float* __restrict__ out) {
    const int lane = threadIdx.x;
    const int b = blockIdx.x;
    const int lidx = (lane < 50) ? lane : 49;
    const char* egb = (const char*)eg + (size_t)b * PB_BYTES;

    // backward state: beta = e_199 basis
    ScanState sb;
    sb.A0 = 0.0f; sb.A1 = 0.0f; sb.A2 = 0.0f;
    sb.A3 = (lane == 49) ? 1.0f : 0.0f;
    sb.S = 0; sb.D = 0;
    // forward state: alpha_0
    ScanState sf = scan_init(in, tgt, lane, b);

    int offF = 800 + lidx * 16;            // fwd: pairs 1.. ascending
    int offB = 1999 * 800 + lidx * 16;     // bwd: pairs 1999.. descending
    uint4 wf[NSLOT], wk[NSLOT];
    #pragma unroll
    for (int j = 0; j < NSLOT; ++j) {
        wf[j] = *(const uint4*)(egb + offF); offF += 800;
        wk[j] = *(const uint4*)(egb + offB); offB -= 800;
    }
    uint2 h0 = *(const uint2*)(egb + lidx * 16 + 8);
    step(sf, LO(h0.x), HI(h0.x), LO(h0.y), HI(h0.y));        // t = 1 (pair0 hi)

    for (int k = 0; k < 49; ++k) {
        #pragma unroll
        for (int j = 0; j < NSLOT; ++j) {
            if ((j & 3) == 0) { renorm(sf, lane); brenorm(sb); }
            uint4 a = wf[j];
            wf[j] = *(const uint4*)(egb + offF); offF += 800;
            uint4 c = wk[j];
            wk[j] = *(const uint4*)(egb + offB); offB -= 800;
            step(sf, LO(a.x), HI(a.x), LO(a.y), HI(a.y));    // fwd t = 2p
            bstep(sb, LO(c.z), HI(c.z), LO(c.w), HI(c.w));   // bwd t = 2p+1 first
            step(sf, LO(a.z), HI(a.z), LO(a.w), HI(a.w));    // fwd t = 2p+1
            bstep(sb, LO(c.x), HI(c.x), LO(c.y), HI(c.y));   // bwd t = 2p
        }
    }
    #pragma unroll
    for (int j = 0; j < NSLOT; ++j) {      // fwd pairs 981..999 full + 1000 lo-only;
        if ((j & 3) == 0) { renorm(sf, lane); brenorm(sb); }  // bwd 1019..1001 full + 1000 hi-only
        uint4 a = wf[j];
        uint4 c = wk[j];
        step(sf, LO(a.x), HI(a.x), LO(a.y), HI(a.y));
        bstep(sb, LO(c.z), HI(c.z), LO(c.w), HI(c.w));
        if (j < NSLOT - 1) {
            step(sf, LO(a.z), HI(a.z), LO(a.w), HI(a.w));
            bstep(sb, LO(c.x), HI(c.x), LO(c.y), HI(c.y));
        }
    }
    renorm(sf, lane);
    brenorm(sb);

    // junction: log2( sum_u alpha_2000[u] * beta_2001[u] ), all in-register
    float d = sf.A0 * sb.A0 + sf.A1 * sb.A1 + sf.A2 * sb.A2 + sf.A3 * sb.A3;
    float ll = (lane < 50) ? hw_log2(fmaxf(d, 1e-38f)) + (float)(sf.S + sb.S)
                           : -1e30f;
    float mx = ll;
    #pragma unroll
    for (int o = 32; o > 0; o >>= 1) mx = fmaxf(mx, __shfl_xor(mx, o));
    float s = (lane < 50) ? hw_exp2(ll - mx) : 0.0f;
    #pragma unroll
    for (int o = 32; o > 0; o >>= 1) s += __shfl_xor(s, o);
    if (lane == 0) atomicAdd(out, -(mx + hw_log2(s)) * (LN2 / 64.0f));
}

// ---- fallback pair (no-workspace path; R7-proven forward core) ----
__global__ __launch_bounds__(256) void lse_sum_kernel(const float* __restrict__ in,
                                                      float* __restrict__ out) {
    const int lane = threadIdx.x & 63;
    const int w = threadIdx.x >> 6;
    const int wid = blockIdx.x * 4 + w;
    const int ROWS = (T_DIM * B_DIM) / 1024;
    const float* p = in + (size_t)wid * ROWS * 64 + lane;
    float acc = 0.0f;
    for (int i = 0; i < ROWS; i += 2) {
        float xa = p[(size_t)i * 64];
        float xb = p[(size_t)(i + 1) * 64];
        float ea = hw_exp2(xa * LOG2E);
        float eb = hw_exp2(xb * LOG2E);
        #pragma unroll
        for (int off = 32; off > 0; off >>= 1) {
            ea += __shfl_xor(ea, off);
            eb += __shfl_xor(eb, off);
        }
        acc += hw_log2(ea) + hw_log2(eb);
    }
    __shared__ float red[4];
    if (lane == 0) red[w] = acc;
    __syncthreads();
    if (threadIdx.x == 0)
        atomicAdd(out, (red[0] + red[1] + red[2] + red[3]) * (LN2 / 64.0f));
}

__global__ __launch_bounds__(64) void scan_fb(const float* __restrict__ in,
                                              const int* __restrict__ tgt,
                                              float* __restrict__ out) {
    const int lane = threadIdx.x;
    const int b = blockIdx.x;
    const int lidx = (lane < 50) ? lane : 49;
    int4 tg = ((const int4*)(tgt + b * U_DIM))[lidx];
    tg.x &= 63; tg.y &= 63; tg.z &= 63; tg.w &= 63;
    ScanState st = scan_init(in, tgt, lane, b);
    const char* inb = (const char*)in;
    int o0 = 16384 + b * 256 + tg.x * 4;
    int o1 = 16384 + b * 256 + tg.y * 4;
    int o2 = 16384 + b * 256 + tg.z * 4;
    int o3 = 16384 + b * 256 + tg.w * 4;
    const int m0 = 3999 * 16384 + b * 256 + tg.x * 4;
    const int m1 = m0 + (tg.y - tg.x) * 4;
    const int m2 = m0 + (tg.z - tg.x) * 4;
    const int m3 = m0 + (tg.w - tg.x) * 4;
    float f0[16], f1[16], f2[16], f3[16];
    #pragma unroll
    for (int j = 0; j < 16; ++j) {
        f0[j] = *(const float*)(inb + min(o0, m0)); o0 += 16384;
        f1[j] = *(const float*)(inb + min(o1, m1)); o1 += 16384;
        f2[j] = *(const float*)(inb + min(o2, m2)); o2 += 16384;
        f3[j] = *(const float*)(inb + min(o3, m3)); o3 += 16384;
    }
    for (int k = 0; k < 249; ++k) {
        #pragma unroll
        for (int j = 0; j < 16; ++j) {
            if (j == 0 || j == 8) renorm(st, lane);
            float e0 = hw_exp2(f0[j] * LOG2E);
            float e1 = hw_exp2(f1[j] * LOG2E);
            float e2 = hw_exp2(f2[j] * LOG2E);
            float e3 = hw_exp2(f3[j] * LOG2E);
            f0[j] = *(const float*)(inb + min(o0, m0)); o0 += 16384;
            f1[j] = *(const float*)(inb + min(o1, m1)); o1 += 16384;
            f2[j] = *(const float*)(inb + min(o2, m2)); o2 += 16384;
            f3[j] = *(const float*)(inb + min(o3, m3)); o3 += 16384;
            step(st, e0, e1, e2, e3);
        }
    }
    #pragma unroll
    for (int j = 0; j < 15; ++j) {
        if (j == 0 || j == 8) renorm(st, lane);
        float e0 = hw_exp2(f0[j] * LOG2E);
        float e1 = hw_exp2(f1[j] * LOG2E);
        float e2 = hw_exp2(f2[j] * LOG2E);
        float e3 = hw_exp2(f3[j] * LOG2E);
        step(st, e0, e1, e2, e3);
    }
    if (lane == 49) {
        float a2 = hw_log2(fmaxf(st.A3, 1e-38f)) + (float)st.S;
        atomicAdd(out, -a2 * (LN2 / 64.0f));
    }
}

extern "C" void kernel_launch(void* const* d_in, const int* in_sizes, int n_in,
                              void* d_out, int out_size, void* d_ws, size_t ws_size,
                              hipStream_t stream) {
    const float* inputs = (const float*)d_in[0];   // (T, B, C) fp32
    const int* targets = (const int*)d_in[1];      // (B, U) int32
    float* out = (float*)d_out;                    // scalar fp32

    (void)hipMemsetAsync(out, 0, sizeof(float), stream);

    const size_t eg_bytes = (size_t)B_DIM * PB_BYTES;   // 102.4 MB
    if (ws_size >= eg_bytes) {
        unsigned* eg = (unsigned*)d_ws;
        prep_kernel<<<2000, 256, 0, stream>>>(inputs, targets, eg, out);
        scan2_kernel<<<B_DIM, 64, 0, stream>>>(inputs, targets, eg, out);
    } else {
        scan_fb<<<B_DIM, 64, 0, stream>>>(inputs, targets, out);
        lse_sum_kernel<<<256, 256, 0, stream>>>(inputs, out);
    }
}

// Round 7
// 187.035 us; speedup vs baseline: 1.3559x; 1.3559x over previous
//
#include <hip/hip_runtime.h>

#define T_DIM 4000
#define B_DIM 64
#define C_DIM 64
#define U_DIM 200
#define LOG2E 1.4426950408889634f
#define LN2 0.6931471805599453f

#define PAIRS 2000                 // pair tp = (t=2tp, t=2tp+1); no pad row
#define PB_BYTES (PAIRS * 800)     // 1.6 MB per batch (50 lanes x 16 B per pair)
#define NSLOT 20                   // uint4 slots per scan wave: 40 steps in flight
#define HALF 10                    // burst bank size (2 banks per NSLOT)

__device__ __forceinline__ float hw_exp2(float x) { return __builtin_amdgcn_exp2f(x); }
__device__ __forceinline__ float hw_log2(float x) { return __builtin_amdgcn_logf(x); }

// DPP: zero-fill (bound_ctrl) lane permute, pure VALU. 0x138=wave_shr:1 (lane l <- l-1),
// 0x130=wave_shl:1 (lane l <- l+1).
template <int CTRL>
__device__ __forceinline__ int dpp_i(int x) {
    return __builtin_amdgcn_update_dpp(0, x, CTRL, 0xF, 0xF, true);
}
template <int CTRL>
__device__ __forceinline__ float dpp_f(float x) {
    return __uint_as_float((unsigned)dpp_i<CTRL>((int)__float_as_uint(x)));
}

__device__ __forceinline__ unsigned rne_bf16(float v) {   // RNE bf16 in hi16
    unsigned b = __float_as_uint(v);
    return b + 0x7FFFu + ((b >> 16) & 1u);
}

// ---------------- prep: coalesced stage -> bf16 LDS tile -> Eg emit + row-lse ----------------
// (R5-proven, absmax 0.0) Block = (bg 0..7, tc 0..249).
__global__ __launch_bounds__(256, 8) void prep_kernel(const float* __restrict__ in,
                                                      const int* __restrict__ tgt,
                                                      unsigned* __restrict__ eg,
                                                      float* __restrict__ out) {
    __shared__ unsigned short exh[16 * 8 * 68];   // bf16 hi16, 68-stride pad
    __shared__ unsigned tgc[400];                 // uchar4-packed targets for 8 batches
    __shared__ float red[4];
    const int tid = threadIdx.x;
    const int bg = blockIdx.x & 7;
    const int tc = blockIdx.x >> 3;
    const int t0 = tc * 16, b0 = bg * 8;

    for (int o = tid; o < 400; o += 256) {
        int4 tv = ((const int4*)tgt)[bg * 400 + o];
        tgc[o] = (unsigned)(tv.x & 63) | ((unsigned)(tv.y & 63) << 8)
               | ((unsigned)(tv.z & 63) << 16) | ((unsigned)(tv.w & 63) << 24);
    }
    #pragma unroll
    for (int k = 0; k < 8; ++k) {
        int flat = k * 256 + tid;              // 0..2047
        int t_l = flat >> 7, i = flat & 127, b_l = i >> 4, q = i & 15;
        float4 v = *(const float4*)(in + (size_t)(t0 + t_l) * 4096 + (b0 + b_l) * 64 + q * 4);
        unsigned ex0 = rne_bf16(hw_exp2(v.x * LOG2E));
        unsigned ex1 = rne_bf16(hw_exp2(v.y * LOG2E));
        unsigned ex2 = rne_bf16(hw_exp2(v.z * LOG2E));
        unsigned ex3 = rne_bf16(hw_exp2(v.w * LOG2E));
        uint2 pk;
        pk.x = (ex0 >> 16) | (ex1 & 0xFFFF0000u);
        pk.y = (ex2 >> 16) | (ex3 & 0xFFFF0000u);
        *(uint2*)&exh[(t_l * 8 + b_l) * 68 + q * 4] = pk;
    }
    __syncthreads();

    {
        float v = 0.0f;
        if (tid < 128) {
            const unsigned* p = (const unsigned*)&exh[tid * 68];
            float s = 0.0f;
            #pragma unroll
            for (int j = 0; j < 32; ++j) {
                unsigned u = p[j];
                s += __uint_as_float(u << 16) + __uint_as_float(u & 0xFFFF0000u);
            }
            v = hw_log2(s);
        }
        #pragma unroll
        for (int o = 32; o > 0; o >>= 1) v += __shfl_xor(v, o);
        if ((tid & 63) == 0) red[tid >> 6] = v;
    }

    {
        const int wv4 = tid >> 6;      // wave 0..3
        const int ln = tid & 63;
        for (int r = wv4; r < 64; r += 4) {
            int b_l = r & 7, tp_l = r >> 3;
            if (ln < 50) {
                unsigned tw = tgc[b_l * 50 + ln];
                int c0 = tw & 255, c1 = (tw >> 8) & 255, c2 = (tw >> 16) & 255, c3 = tw >> 24;
                const unsigned short* plo = &exh[(tp_l * 16 + b_l) * 68];   // t = 2*tp_l
                const unsigned short* phi = plo + 8 * 68;                   // t = 2*tp_l + 1
                uint4 w;
                w.x = (unsigned)plo[c0] | ((unsigned)plo[c1] << 16);
                w.y = (unsigned)plo[c2] | ((unsigned)plo[c3] << 16);
                w.z = (unsigned)phi[c0] | ((unsigned)phi[c1] << 16);
                w.w = (unsigned)phi[c2] | ((unsigned)phi[c3] << 16);
                *(uint4*)((char*)eg + (size_t)(b0 + b_l) * PB_BYTES
                          + (size_t)(tc * 8 + tp_l) * 800 + ln * 16) = w;
            }
        }
    }
    __syncthreads();
    if (tid == 0)
        atomicAdd(out, (red[0] + red[1] + red[2] + red[3]) * (LN2 / 64.0f));
}

// ---- forward scan core (R0-proven, absmax 0.0) ----
struct ScanState { float A0, A1, A2, A3; int S, D; };

__device__ __forceinline__ void renorm(ScanState& st, int lane) {
    float m = fmaxf(fmaxf(st.A0, st.A1), fmaxf(st.A2, st.A3));
    int e = (int)((__float_as_uint(m) >> 23) & 0xFFu);
    int cand = st.S + e - 127;
    int snb = dpp_i<0x138>(st.S);
    if (lane == 0) snb = -(1 << 28);
    int snew = max(cand, snb);
    int k = st.S - snew;
    st.A0 = ldexpf(st.A0, k);
    st.A1 = ldexpf(st.A1, k);
    st.A2 = ldexpf(st.A2, k);
    st.A3 = ldexpf(st.A3, k);
    st.S = snew;
    st.D = min(dpp_i<0x138>(snew) - snew, 60);
}

__device__ __forceinline__ void step(ScanState& st, float e0, float e1, float e2, float e3) {
    float sh = ldexpf(dpp_f<0x138>(st.A3), st.D);
    sh = fminf(sh, 1.125899906842624e15f);         // 2^50; fminf absorbs inf
    float t0 = st.A0 + sh;
    float t1 = st.A1 + st.A0;
    float t2 = st.A2 + st.A1;
    float t3 = st.A3 + st.A2;
    st.A0 = e0 * t0; st.A1 = e1 * t1; st.A2 = e2 * t2; st.A3 = e3 * t3;
}

// ---- backward core: beta^T <- beta^T M_t; cross-lane term from lane l+1 via 0x130 ----
__device__ __forceinline__ void brenorm(ScanState& st) {
    float m = fmaxf(fmaxf(st.A0, st.A1), fmaxf(st.A2, st.A3));
    int e = (int)((__float_as_uint(m) >> 23) & 0xFFu);
    int cand = st.S + e - 127;
    int snb = dpp_i<0x130>(st.S);                  // lane63 gets 0 (junk side, harmless)
    int snew = max(cand, snb);
    int k = st.S - snew;
    st.A0 = ldexpf(st.A0, k);
    st.A1 = ldexpf(st.A1, k);
    st.A2 = ldexpf(st.A2, k);
    st.A3 = ldexpf(st.A3, k);
    st.S = snew;
    st.D = min(dpp_i<0x130>(snew) - snew, 60);
}

__device__ __forceinline__ void bstep(ScanState& st, float e0, float e1, float e2, float e3) {
    float e4s = fminf(ldexpf(dpp_f<0x130>(e0), st.D), 1.125899906842624e15f);
    float b0n = dpp_f<0x130>(st.A0);
    float g0 = e0 * st.A0, g1 = e1 * st.A1, g2 = e2 * st.A2, g3 = e3 * st.A3;
    st.A0 = g0 + g1; st.A1 = g1 + g2; st.A2 = g2 + g3; st.A3 = g3 + e4s * b0n;
}

__device__ __forceinline__ ScanState scan_init(const float* in, const int* tgt, int lane, int b) {
    float v0 = in[b * 64 + (tgt[b * U_DIM] & 63)];
    ScanState st;
    st.A0 = (lane == 0) ? hw_exp2(v0 * LOG2E) : 0.0f;
    st.A1 = 0.0f; st.A2 = 0.0f; st.A3 = 0.0f;
    st.S = 0; st.D = 0;
    return st;
}

#define LO(x) __uint_as_float((x) << 16)
#define HI(x) __uint_as_float((x) & 0xFFFF0000u)

// Meet-in-the-middle scan (R0 core, burst-load variant): wave0 = forward (t=1..2000),
// wave1 = backward (t=3999..2001). ONLY change vs the proven R0 kernel: slot reloads are
// issued in bursts of 10 AFTER consuming that bank (double-buffered halves), instead of
// one reload per j. Record->slot mapping, consumption order, and all math are identical
// (bit-identical result). Goal: one counted vmcnt per half instead of per-j waits.
__global__ __launch_bounds__(128, 1) void scan2_kernel(const float* __restrict__ in,
                                                       const int* __restrict__ tgt,
                                                       const unsigned* __restrict__ eg,
                                                       float* __restrict__ out) {
    __shared__ float jb0[64], jb1[64], jb2[64], jb3[64];
    __shared__ int jsb[64];
    const int lane = threadIdx.x & 63;
    const int wv = threadIdx.x >> 6;
    const int b = blockIdx.x;
    const int lidx = (lane < 50) ? lane : 49;
    const char* egb = (const char*)eg + (size_t)b * PB_BYTES;

    ScanState st;
    if (wv == 1) {
        // ---------- backward: beta = e_199; pairs 1999 down to 1000(hi only) ----------
        st.A0 = 0.0f; st.A1 = 0.0f; st.A2 = 0.0f;
        st.A3 = (lane == 49) ? 1.0f : 0.0f;
        st.S = 0; st.D = 0;
        int off = 1999 * 800 + lidx * 16;
        uint4 wb[NSLOT];
        #pragma unroll
        for (int j = 0; j < NSLOT; ++j) { wb[j] = *(const uint4*)(egb + off); off -= 800; }
        for (int k = 0; k < 49; ++k) {
            // half 0: consume slots 0..9, then burst-reload them
            #pragma unroll
            for (int j = 0; j < HALF; ++j) {
                if ((j & 3) == 0) brenorm(st);
                uint4 w = wb[j];
                bstep(st, LO(w.z), HI(w.z), LO(w.w), HI(w.w));   // t = 2p+1 first
                bstep(st, LO(w.x), HI(w.x), LO(w.y), HI(w.y));   // then t = 2p
            }
            #pragma unroll
            for (int j = 0; j < HALF; ++j) { wb[j] = *(const uint4*)(egb + off); off -= 800; }
            // half 1: consume slots 10..19, then burst-reload them
            #pragma unroll
            for (int j = HALF; j < NSLOT; ++j) {
                if ((j & 3) == 0) brenorm(st);
                uint4 w = wb[j];
                bstep(st, LO(w.z), HI(w.z), LO(w.w), HI(w.w));
                bstep(st, LO(w.x), HI(w.x), LO(w.y), HI(w.y));
            }
            #pragma unroll
            for (int j = HALF; j < NSLOT; ++j) { wb[j] = *(const uint4*)(egb + off); off -= 800; }
        }
        #pragma unroll
        for (int j = 0; j < NSLOT; ++j) {      // pairs 1019..1001 full, 1000 hi-only
            if ((j & 3) == 0) brenorm(st);
            uint4 w = wb[j];
            bstep(st, LO(w.z), HI(w.z), LO(w.w), HI(w.w));
            if (j < NSLOT - 1) bstep(st, LO(w.x), HI(w.x), LO(w.y), HI(w.y));
        }
        brenorm(st);
        jb0[lane] = st.A0; jb1[lane] = st.A1; jb2[lane] = st.A2; jb3[lane] = st.A3;
        jsb[lane] = st.S;
    } else {
        // ---------- forward: alpha_0 -> t=1 (pair0 hi) -> pairs 1..999 -> pair1000 lo ----------
        st = scan_init(in, tgt, lane, b);
        int off = 800 + lidx * 16;
        uint4 wb[NSLOT];
        #pragma unroll
        for (int j = 0; j < NSLOT; ++j) { wb[j] = *(const uint4*)(egb + off); off += 800; }
        uint2 h0 = *(const uint2*)(egb + lidx * 16 + 8);
        step(st, LO(h0.x), HI(h0.x), LO(h0.y), HI(h0.y));        // t = 1
        for (int k = 0; k < 49; ++k) {
            #pragma unroll
            for (int j = 0; j < HALF; ++j) {
                if ((j & 3) == 0) renorm(st, lane);
                uint4 w = wb[j];
                step(st, LO(w.x), HI(w.x), LO(w.y), HI(w.y));    // t = 2p
                step(st, LO(w.z), HI(w.z), LO(w.w), HI(w.w));    // t = 2p+1
            }
            #pragma unroll
            for (int j = 0; j < HALF; ++j) { wb[j] = *(const uint4*)(egb + off); off += 800; }
            #pragma unroll
            for (int j = HALF; j < NSLOT; ++j) {
                if ((j & 3) == 0) renorm(st, lane);
                uint4 w = wb[j];
                step(st, LO(w.x), HI(w.x), LO(w.y), HI(w.y));
                step(st, LO(w.z), HI(w.z), LO(w.w), HI(w.w));
            }
            #pragma unroll
            for (int j = HALF; j < NSLOT; ++j) { wb[j] = *(const uint4*)(egb + off); off += 800; }
        }
        #pragma unroll
        for (int j = 0; j < NSLOT; ++j) {      // pairs 981..999 full, 1000 lo-only
            if ((j & 3) == 0) renorm(st, lane);
            uint4 w = wb[j];
            step(st, LO(w.x), HI(w.x), LO(w.y), HI(w.y));
            if (j < NSLOT - 1) step(st, LO(w.z), HI(w.z), LO(w.w), HI(w.w));
        }
        renorm(st, lane);
    }
    __syncthreads();
    if (wv == 0) {
        // junction: log2( sum_u alpha_2000[u] * beta_2001[u] )
        float d = st.A0 * jb0[lane] + st.A1 * jb1[lane]
                + st.A2 * jb2[lane] + st.A3 * jb3[lane];
        float ll = (lane < 50) ? hw_log2(fmaxf(d, 1e-38f)) + (float)(st.S + jsb[lane])
                               : -1e30f;
        float mx = ll;
        #pragma unroll
        for (int o = 32; o > 0; o >>= 1) mx = fmaxf(mx, __shfl_xor(mx, o));
        float s = (lane < 50) ? hw_exp2(ll - mx) : 0.0f;
        #pragma unroll
        for (int o = 32; o > 0; o >>= 1) s += __shfl_xor(s, o);
        if (lane == 0) atomicAdd(out, -(mx + hw_log2(s)) * (LN2 / 64.0f));
    }
}

// ---- fallback pair (no-workspace path; R7-proven forward core) ----
__global__ __launch_bounds__(256) void lse_sum_kernel(const float* __restrict__ in,
                                                      float* __restrict__ out) {
    const int lane = threadIdx.x & 63;
    const int w = threadIdx.x >> 6;
    const int wid = blockIdx.x * 4 + w;
    const int ROWS = (T_DIM * B_DIM) / 1024;
    const float* p = in + (size_t)wid * ROWS * 64 + lane;
    float acc = 0.0f;
    for (int i = 0; i < ROWS; i += 2) {
        float xa = p[(size_t)i * 64];
        float xb = p[(size_t)(i + 1) * 64];
        float ea = hw_exp2(xa * LOG2E);
        float eb = hw_exp2(xb * LOG2E);
        #pragma unroll
        for (int off = 32; off > 0; off >>= 1) {
            ea += __shfl_xor(ea, off);
            eb += __shfl_xor(eb, off);
        }
        acc += hw_log2(ea) + hw_log2(eb);
    }
    __shared__ float red[4];
    if (lane == 0) red[w] = acc;
    __syncthreads();
    if (threadIdx.x == 0)
        atomicAdd(out, (red[0] + red[1] + red[2] + red[3]) * (LN2 / 64.0f));
}

__global__ __launch_bounds__(64) void scan_fb(const float* __restrict__ in,
                                              const int* __restrict__ tgt,
                                              float* __restrict__ out) {
    const int lane = threadIdx.x;
    const int b = blockIdx.x;
    const int lidx = (lane < 50) ? lane : 49;
    int4 tg = ((const int4*)(tgt + b * U_DIM))[lidx];
    tg.x &= 63; tg.y &= 63; tg.z &= 63; tg.w &= 63;
    ScanState st = scan_init(in, tgt, lane, b);
    const char* inb = (const char*)in;
    int o0 = 16384 + b * 256 + tg.x * 4;
    int o1 = 16384 + b * 256 + tg.y * 4;
    int o2 = 16384 + b * 256 + tg.z * 4;
    int o3 = 16384 + b * 256 + tg.w * 4;
    const int m0 = 3999 * 16384 + b * 256 + tg.x * 4;
    const int m1 = m0 + (tg.y - tg.x) * 4;
    const int m2 = m0 + (tg.z - tg.x) * 4;
    const int m3 = m0 + (tg.w - tg.x) * 4;
    float f0[16], f1[16], f2[16], f3[16];
    #pragma unroll
    for (int j = 0; j < 16; ++j) {
        f0[j] = *(const float*)(inb + min(o0, m0)); o0 += 16384;
        f1[j] = *(const float*)(inb + min(o1, m1)); o1 += 16384;
        f2[j] = *(const float*)(inb + min(o2, m2)); o2 += 16384;
        f3[j] = *(const float*)(inb + min(o3, m3)); o3 += 16384;
    }
    for (int k = 0; k < 249; ++k) {
        #pragma unroll
        for (int j = 0; j < 16; ++j) {
            if (j == 0 || j == 8) renorm(st, lane);
            float e0 = hw_exp2(f0[j] * LOG2E);
            float e1 = hw_exp2(f1[j] * LOG2E);
            float e2 = hw_exp2(f2[j] * LOG2E);
            float e3 = hw_exp2(f3[j] * LOG2E);
            f0[j] = *(const float*)(inb + min(o0, m0)); o0 += 16384;
            f1[j] = *(const float*)(inb + min(o1, m1)); o1 += 16384;
            f2[j] = *(const float*)(inb + min(o2, m2)); o2 += 16384;
            f3[j] = *(const float*)(inb + min(o3, m3)); o3 += 16384;
            step(st, e0, e1, e2, e3);
        }
    }
    #pragma unroll
    for (int j = 0; j < 15; ++j) {
        if (j == 0 || j == 8) renorm(st, lane);
        float e0 = hw_exp2(f0[j] * LOG2E);
        float e1 = hw_exp2(f1[j] * LOG2E);
        float e2 = hw_exp2(f2[j] * LOG2E);
        float e3 = hw_exp2(f3[j] * LOG2E);
        step(st, e0, e1, e2, e3);
    }
    if (lane == 49) {
        float a2 = hw_log2(fmaxf(st.A3, 1e-38f)) + (float)st.S;
        atomicAdd(out, -a2 * (LN2 / 64.0f));
    }
}

extern "C" void kernel_launch(void* const* d_in, const int* in_sizes, int n_in,
                              void* d_out, int out_size, void* d_ws, size_t ws_size,
                              hipStream_t stream) {
    const float* inputs = (const float*)d_in[0];   // (T, B, C) fp32
    const int* targets = (const int*)d_in[1];      // (B, U) int32
    float* out = (float*)d_out;                    // scalar fp32

    (void)hipMemsetAsync(out, 0, sizeof(float), stream);

    const size_t eg_bytes = (size_t)B_DIM * PB_BYTES;   // 102.4 MB
    if (ws_size >= eg_bytes) {
        unsigned* eg = (unsigned*)d_ws;
        prep_kernel<<<2000, 256, 0, stream>>>(inputs, targets, eg, out);
        scan2_kernel<<<B_DIM, 128, 0, stream>>>(inputs, targets, eg, out);
    } else {
        scan_fb<<<B_DIM, 64, 0, stream>>>(inputs, targets, out);
        lse_sum_kernel<<<256, 256, 0, stream>>>(inputs, out);
    }
}